// Round 1
// baseline (1078.773 us; speedup 1.0000x reference)
//
#include <hip/hip_runtime.h>
#include <math.h>

// Problem constants
#define B_    512
#define W_    4
#define KD_   64
#define NC_   32
#define D_    256
#define NN_   16
#define NH_   8
#define AD_   32
#define HOPS_ 4
#define DH_   32
#define DFF_  1024
#define P_    2560
#define BW_   2048   // B*W
#define MAXT2_ 176   // worst-case 16-row M-tiles: P/16 + (NN-1) = 175, rounded to %8==0

#define INV_SQRT_DH 0.17677669529663687f  // 1/sqrt(32)

// ---------------- block-wide sum over 256 threads ----------------
__device__ __forceinline__ float block_sum256(float v, float* red) {
#pragma unroll
  for (int off = 32; off > 0; off >>= 1) v += __shfl_xor(v, off, 64);
  int wid = threadIdx.x >> 6;
  if ((threadIdx.x & 63) == 0) red[wid] = v;
  __syncthreads();
  float s = red[0] + red[1] + red[2] + red[3];
  __syncthreads();
  return s;
}

__device__ __forceinline__ float gelu_tanh(float v) {
  float u = 0.7978845608028654f * (v + 0.044715f * v * v * v);
  return 0.5f * v * (1.0f + tanhf(u));
}

// ---------------- encode writers + queries -> h, node ----------------
__global__ __launch_bounds__(256) void encode_kernel(
    const float* __restrict__ query_keys, const float* __restrict__ writer_keys,
    const float* __restrict__ kpw, const float* __restrict__ kpb,
    const float* __restrict__ ce, const float* __restrict__ re,
    const float* __restrict__ sne, const float* __restrict__ ilg,
    const float* __restrict__ ilb, const int* __restrict__ qsn,
    const int* __restrict__ wl, const int* __restrict__ wsn,
    float* __restrict__ h, int* __restrict__ node) {
  int p = blockIdx.x, t = threadIdx.x;
  __shared__ float fk[KD_];
  __shared__ float red[4];
  const float* key;
  int lab = -1, sn, role;
  if (p < BW_) { key = writer_keys + (size_t)p * KD_; lab = wl[p]; sn = wsn[p]; role = 0; }
  else { int b = p - BW_; key = query_keys + (size_t)b * KD_; sn = qsn[b]; role = 1; }
  if (t < KD_) fk[t] = key[t];
  __syncthreads();

  float acc = kpb[t] + sne[sn * D_ + t] + re[role * D_ + t];
  if (lab >= 0) acc += ce[lab * D_ + t];
#pragma unroll 8
  for (int i = 0; i < KD_; i++) acc += fk[i] * kpw[i * D_ + t];

  float mean = block_sum256(acc, red) * (1.0f / D_);
  float d = acc - mean;
  float var = block_sum256(d * d, red) * (1.0f / D_);
  float xn = d * (1.0f / sqrtf(var + 1e-5f));

  float sw = 0.0f;
  if (t < KD_) sw = fk[t];
  else if (lab >= 0 && t < KD_ + NC_) sw = (t - KD_ == lab) ? 1.0f : 0.0f;

  h[(size_t)p * D_ + t] = xn * ilg[t] + ilb[t] + sw;
  if (t == 0) node[p] = sn;
}

// ---------------- group packets by node + 16-row tile worklist + inverse map -
__global__ __launch_bounds__(256) void sort_kernel(const int* __restrict__ node,
                                                   int* __restrict__ order,
                                                   int* __restrict__ invord,
                                                   int* __restrict__ offs,
                                                   int* __restrict__ cnts,
                                                   int* __restrict__ tnode,
                                                   int* __restrict__ tstart,
                                                   int* __restrict__ tend,
                                                   int* __restrict__ ntiles) {
  __shared__ int c[NN_], o[NN_], cur[NN_];
  int t = threadIdx.x;
  if (t < NN_) c[t] = 0;
  __syncthreads();
  for (int p = t; p < P_; p += 256) atomicAdd(&c[node[p]], 1);
  __syncthreads();
  if (t == 0) {
    int s = 0;
    for (int n = 0; n < NN_; n++) { o[n] = s; cur[n] = s; s += c[n]; }
    int idx = 0;
    for (int n = 0; n < NN_; n++) {
      int e = o[n] + c[n];
      for (int m0 = o[n]; m0 < e; m0 += 16) {
        tnode[idx] = n; tstart[idx] = m0; tend[idx] = e; idx++;
      }
    }
    ntiles[0] = idx;
  }
  __syncthreads();
  if (t < NN_) { cnts[t] = c[t]; offs[t] = o[t]; }
  for (int p = t; p < P_; p += 256) {
    int r = atomicAdd(&cur[node[p]], 1);
    order[r] = p;
    invord[p] = r;
  }
}

// ---------------- LN with per-node affine, wave-per-row, SORTED out ---------
__global__ __launch_bounds__(256) void ln_affine(const float* __restrict__ h,
                                                 const float* __restrict__ g,
                                                 const float* __restrict__ b,
                                                 const int* __restrict__ node,
                                                 const int* __restrict__ order,
                                                 float* __restrict__ x) {
  int sp = blockIdx.x * 4 + (threadIdx.x >> 6);
  int lane = threadIdx.x & 63;
  int p = order[sp];
  int n = node[p];
  float4 v = *(const float4*)&h[(size_t)p * D_ + lane * 4];
  float s = v.x + v.y + v.z + v.w;
#pragma unroll
  for (int off = 32; off > 0; off >>= 1) s += __shfl_xor(s, off, 64);
  float mean = s * (1.0f / D_);
  float4 d = make_float4(v.x - mean, v.y - mean, v.z - mean, v.w - mean);
  float vr = d.x * d.x + d.y * d.y + d.z * d.z + d.w * d.w;
#pragma unroll
  for (int off = 32; off > 0; off >>= 1) vr += __shfl_xor(vr, off, 64);
  float inv = 1.0f / sqrtf(vr * (1.0f / D_) + 1e-5f);
  float4 gg = *(const float4*)&g[n * D_ + lane * 4];
  float4 bb = *(const float4*)&b[n * D_ + lane * 4];
  float4 o;
  o.x = d.x * inv * gg.x + bb.x;
  o.y = d.y * inv * gg.y + bb.y;
  o.z = d.z * inv * gg.z + bb.z;
  o.w = d.w * inv * gg.w + bb.w;
  *(float4*)&x[(size_t)sp * D_ + lane * 4] = o;
}

// ---------------- grouped linear v2: LDS-free, VALU-bound -------------------
// 16-row M-tiles, 4 waves/block, 4 rows per wave (x loads are wave-uniform
// broadcast dwordx4), lane j covers 4 contiguous cols (W loads: wave reads
// 1KiB contiguous per k-row, L1/L2/L3-cached, zero LDS, zero barriers).
// KSPLIT: z=0 main (bias/act/resid), z=1 raw partial -> pbuf (sorted space).
// XMODE 1: x[p] + xaux[invord[p]] (dense packet space, PER_NODE=0 only).
template <int DIN, int DOUT, int ACT, int RESID, int PER_NODE, int KSPLIT, int XMODE>
__global__ __launch_bounds__(256) void glin2(const float* __restrict__ x,
                                             const float* __restrict__ W,
                                             const float* __restrict__ bias,
                                             float* __restrict__ out,
                                             float* __restrict__ pbuf,
                                             const float* __restrict__ xaux,
                                             const int* __restrict__ order,
                                             const int* __restrict__ invord,
                                             const int* __restrict__ tnode,
                                             const int* __restrict__ tstart,
                                             const int* __restrict__ tend,
                                             const int* __restrict__ ntiles) {
  constexpr int KLEN = DIN / KSPLIT;

  // bijective XCD swizzle over gridDim.x (gridDim.x % 8 == 0 by construction):
  // consecutive same-node tiles cluster on one XCD's L2.
  int gx = gridDim.x;
  int bid = blockIdx.x;
  int ti = (bid & 7) * (gx >> 3) + (bid >> 3);

  int n, s0, rows;
  if (PER_NODE) {
    if (ti >= ntiles[0]) return;
    n = tnode[ti];
    s0 = tstart[ti];
    int e = tend[ti];
    rows = e - s0;
    if (rows > 16) rows = 16;
  } else {
    n = 0;
    s0 = ti * 16;
    rows = 16;
  }
  int jb = blockIdx.y * 256;
  int kz = (KSPLIT > 1) ? blockIdx.z : 0;
  int k0 = kz * KLEN;

  int tid = threadIdx.x;
  int wv = __builtin_amdgcn_readfirstlane((int)(tid >> 6));  // wave id, uniform
  int j4 = (tid & 63) << 2;                                  // my 4 cols in [0,256)

  const float* Wp = W + (size_t)n * DIN * DOUT + (size_t)k0 * DOUT + jb + j4;

  // x row bases: 4 rows per wave, wave-uniform addresses (broadcast loads)
  const float* xr0;
  const float* xr1;
  const float* xr2;
  const float* xr3;
  const float* ar0 = nullptr;
  const float* ar1 = nullptr;
  const float* ar2 = nullptr;
  const float* ar3 = nullptr;
  {
    int rbase = s0 + (wv << 2);  // rows rbase..rbase+3 (buffers padded +16 rows)
    xr0 = x + (size_t)(rbase + 0) * DIN + k0;
    xr1 = x + (size_t)(rbase + 1) * DIN + k0;
    xr2 = x + (size_t)(rbase + 2) * DIN + k0;
    xr3 = x + (size_t)(rbase + 3) * DIN + k0;
    if (XMODE == 1) {
      ar0 = xaux + (size_t)invord[rbase + 0] * DIN + k0;
      ar1 = xaux + (size_t)invord[rbase + 1] * DIN + k0;
      ar2 = xaux + (size_t)invord[rbase + 2] * DIN + k0;
      ar3 = xaux + (size_t)invord[rbase + 3] * DIN + k0;
    }
  }

  float4 a0 = make_float4(0.f, 0.f, 0.f, 0.f);
  float4 a1 = a0, a2 = a0, a3 = a0;
  float4 wc0, wc1, wc2, wc3, xc0, xc1, xc2, xc3;

#define LDW_(kk, w0, w1, w2, w3)                              \
  w0 = *(const float4*)(Wp + (size_t)((kk) + 0) * DOUT);      \
  w1 = *(const float4*)(Wp + (size_t)((kk) + 1) * DOUT);      \
  w2 = *(const float4*)(Wp + (size_t)((kk) + 2) * DOUT);      \
  w3 = *(const float4*)(Wp + (size_t)((kk) + 3) * DOUT);

#define LDX1_(kk, ptr, aptr, dst)                             \
  dst = *(const float4*)((ptr) + (kk));                       \
  if (XMODE == 1) {                                           \
    float4 _a = *(const float4*)((aptr) + (kk));              \
    dst.x += _a.x; dst.y += _a.y; dst.z += _a.z; dst.w += _a.w; \
  }

#define LDX_(kk, x0, x1, x2, x3)   \
  LDX1_(kk, xr0, ar0, x0)          \
  LDX1_(kk, xr1, ar1, x1)          \
  LDX1_(kk, xr2, ar2, x2)          \
  LDX1_(kk, xr3, ar3, x3)

  LDW_(0, wc0, wc1, wc2, wc3);
  LDX_(0, xc0, xc1, xc2, xc3);

#pragma unroll 2
  for (int kk = 0; kk < KLEN; kk += 4) {
    float4 wn0, wn1, wn2, wn3, xn0, xn1, xn2, xn3;
    bool more = (kk + 4 < KLEN);
    if (more) {
      LDW_(kk + 4, wn0, wn1, wn2, wn3);
      LDX_(kk + 4, xn0, xn1, xn2, xn3);
    }
#pragma unroll
    for (int t = 0; t < 4; ++t) {
      float4 wt = (t == 0) ? wc0 : (t == 1) ? wc1 : (t == 2) ? wc2 : wc3;
      float f0 = (t == 0) ? xc0.x : (t == 1) ? xc0.y : (t == 2) ? xc0.z : xc0.w;
      float f1 = (t == 0) ? xc1.x : (t == 1) ? xc1.y : (t == 2) ? xc1.z : xc1.w;
      float f2 = (t == 0) ? xc2.x : (t == 1) ? xc2.y : (t == 2) ? xc2.z : xc2.w;
      float f3 = (t == 0) ? xc3.x : (t == 1) ? xc3.y : (t == 2) ? xc3.z : xc3.w;
      a0.x += f0 * wt.x; a0.y += f0 * wt.y; a0.z += f0 * wt.z; a0.w += f0 * wt.w;
      a1.x += f1 * wt.x; a1.y += f1 * wt.y; a1.z += f1 * wt.z; a1.w += f1 * wt.w;
      a2.x += f2 * wt.x; a2.y += f2 * wt.y; a2.z += f2 * wt.z; a2.w += f2 * wt.w;
      a3.x += f3 * wt.x; a3.y += f3 * wt.y; a3.z += f3 * wt.z; a3.w += f3 * wt.w;
    }
    if (more) {
      wc0 = wn0; wc1 = wn1; wc2 = wn2; wc3 = wn3;
      xc0 = xn0; xc1 = xn1; xc2 = xn2; xc3 = xn3;
    }
  }
#undef LDW_
#undef LDX1_
#undef LDX_

  int jcol = jb + j4;
  bool main_part = (KSPLIT == 1) || (kz == 0);
  float4 bv = make_float4(0.f, 0.f, 0.f, 0.f);
  if (main_part) bv = *(const float4*)(bias + (size_t)n * DOUT + jcol);

#pragma unroll
  for (int r = 0; r < 4; ++r) {
    int lr = (wv << 2) + r;
    if (PER_NODE && lr >= rows) continue;
    float4 av = (r == 0) ? a0 : (r == 1) ? a1 : (r == 2) ? a2 : a3;
    if (main_part) {
      float4 v = make_float4(av.x + bv.x, av.y + bv.y, av.z + bv.z, av.w + bv.w);
      if (ACT == 1) {
        v.x = gelu_tanh(v.x); v.y = gelu_tanh(v.y);
        v.z = gelu_tanh(v.z); v.w = gelu_tanh(v.w);
      }
      if (RESID) {
        int pp = PER_NODE ? order[s0 + lr] : (s0 + lr);
        float* op = out + (size_t)pp * DOUT + jcol;
        float4 old = *(const float4*)op;
        *(float4*)op = make_float4(v.x + old.x, v.y + old.y, v.z + old.z, v.w + old.w);
      } else {
        *(float4*)(out + (size_t)(s0 + lr) * DOUT + jcol) = v;
      }
    } else {
      // raw partial, sorted space, no bias
      *(float4*)(pbuf + (size_t)(s0 + lr) * DOUT + jcol) = av;
    }
  }
}

// ---------------- same-node attention, flash-style, sorted qkv/ao ----------
#define ATS 36  // padded LDS stride (floats): multiple of 4 (float4 align), !=32 (banks)
__global__ __launch_bounds__(256) void attn_kernel(const float* __restrict__ qkv,
                                                   const int* __restrict__ node,
                                                   const int* __restrict__ order,
                                                   const int* __restrict__ offs,
                                                   const int* __restrict__ cnts,
                                                   float* __restrict__ ao) {
  __shared__ float qs[32 * ATS];   // Q row-major [r][d]
  __shared__ float kts[32 * ATS];  // K transposed [d][j]
  __shared__ float vs[32 * ATS];   // V row-major [j][d]
  __shared__ float ps[32 * ATS];   // P row-major [r][j] (wave-coherent use)
  __shared__ int glo[32], ghi[32];

  int t = threadIdx.x;
  int r = t >> 3;          // my q-row (and my staging key-row)
  int j4 = (t & 7) * 4;    // my 4 score-cols == my 4 output dims
  int r0 = blockIdx.x * 32;
  int hd = blockIdx.y;

  if (t < 32) {
    int n = node[order[r0 + t]];
    glo[t] = offs[n];
    ghi[t] = offs[n] + cnts[n];
  }
  __syncthreads();

  {  // Q tile: sorted row r0+r, coalesced
    const float* qp = &qkv[(size_t)(r0 + r) * 768 + hd * 32 + j4];
    float4 q4 = *(const float4*)qp;
    q4.x *= INV_SQRT_DH; q4.y *= INV_SQRT_DH; q4.z *= INV_SQRT_DH; q4.w *= INV_SQRT_DH;
    *(float4*)&qs[r * ATS + j4] = q4;
  }

  int lo = glo[0];
  int hi = ghi[31];
  int myglo = glo[r], myghi = ghi[r];

  float4 o4 = {0.f, 0.f, 0.f, 0.f};
  float mrow = -1e30f, lrow = 0.f;

  for (int kt = lo; kt < hi; kt += 32) {
    int sj = kt + r;
    float4 k4 = {0.f, 0.f, 0.f, 0.f}, v4 = {0.f, 0.f, 0.f, 0.f};
    if (sj < hi) {
      const float* kp = &qkv[(size_t)sj * 768 + 256 + hd * 32 + j4];
      k4 = *(const float4*)kp;
      v4 = *(const float4*)(kp + 256);
    }
    __syncthreads();
    kts[(j4 + 0) * ATS + r] = k4.x;
    kts[(j4 + 1) * ATS + r] = k4.y;
    kts[(j4 + 2) * ATS + r] = k4.z;
    kts[(j4 + 3) * ATS + r] = k4.w;
    *(float4*)&vs[r * ATS + j4] = v4;
    __syncthreads();

    float s0 = 0.f, s1 = 0.f, s2 = 0.f, s3 = 0.f;
#pragma unroll 8
    for (int d = 0; d < 32; d++) {
      float qv = qs[r * ATS + d];
      float4 kv = *(const float4*)&kts[d * ATS + j4];
      s0 += qv * kv.x; s1 += qv * kv.y; s2 += qv * kv.z; s3 += qv * kv.w;
    }
    int c0 = kt + j4;
    if (c0 + 0 < myglo || c0 + 0 >= myghi) s0 = -1e30f;
    if (c0 + 1 < myglo || c0 + 1 >= myghi) s1 = -1e30f;
    if (c0 + 2 < myglo || c0 + 2 >= myghi) s2 = -1e30f;
    if (c0 + 3 < myglo || c0 + 3 >= myghi) s3 = -1e30f;

    float mx = fmaxf(fmaxf(s0, s1), fmaxf(s2, s3));
#pragma unroll
    for (int off = 4; off > 0; off >>= 1) mx = fmaxf(mx, __shfl_xor(mx, off, 8));
    float mnew = fmaxf(mrow, mx);
    float alpha = __expf(mrow - mnew);
    float p0 = __expf(s0 - mnew), p1 = __expf(s1 - mnew);
    float p2 = __expf(s2 - mnew), p3 = __expf(s3 - mnew);
    float ls = p0 + p1 + p2 + p3;
#pragma unroll
    for (int off = 4; off > 0; off >>= 1) ls += __shfl_xor(ls, off, 8);
    lrow = lrow * alpha + ls;
    mrow = mnew;
    o4.x *= alpha; o4.y *= alpha; o4.z *= alpha; o4.w *= alpha;

    *(float4*)&ps[r * ATS + j4] = make_float4(p0, p1, p2, p3);
#pragma unroll 8
    for (int j = 0; j < 32; j++) {
      float pj = ps[r * ATS + j];
      float4 vv = *(const float4*)&vs[j * ATS + j4];
      o4.x += pj * vv.x; o4.y += pj * vv.y; o4.z += pj * vv.z; o4.w += pj * vv.w;
    }
  }

  float inv = 1.f / lrow;
  o4.x *= inv; o4.y *= inv; o4.z *= inv; o4.w *= inv;
  *(float4*)&ao[(size_t)(r0 + r) * D_ + hd * 32 + j4] = o4;  // sorted space
}

// ---------------- routing (folds fc2 split-K partial): -----------------------
__global__ __launch_bounds__(256) void route_kernel(float* __restrict__ h,
                                                    const float* __restrict__ pbuf,
                                                    const int* __restrict__ invord,
                                                    const float* __restrict__ dir_w,
                                                    const float* __restrict__ dir_b,
                                                    const float* __restrict__ at,
                                                    const float* __restrict__ mag_w,
                                                    const float* __restrict__ mag_b,
                                                    const float* __restrict__ delta,
                                                    int* __restrict__ node) {
  int p = blockIdx.x, t = threadIdx.x;
  __shared__ float hs[D_];
  __shared__ float dpart[8][AD_];
  __shared__ float dirs[AD_];
  __shared__ float scs[NN_];
  __shared__ float red[4];
  float hv = h[(size_t)p * D_ + t] + pbuf[(size_t)invord[p] * D_ + t];
  hs[t] = hv;
  __syncthreads();

  int j = t & 31, seg = t >> 5;
  float part = 0.0f;
#pragma unroll 8
  for (int i = 0; i < 32; i++) {
    int ii = seg * 32 + i;
    part += hs[ii] * dir_w[ii * D_ + j];
  }
  dpart[seg][j] = part;
  __syncthreads();
  if (t < AD_) {
    float s = dir_b[t];
#pragma unroll
    for (int g = 0; g < 8; g++) s += dpart[g][t];
    dirs[t] = s;
  }
  __syncthreads();
  if (t < NN_) {
    float s = 0.0f;
#pragma unroll
    for (int a = 0; a < AD_; a++) s += dirs[a] * at[t * AD_ + a];
    scs[t] = s;
  }
  __syncthreads();
  if (t == 0) {
    float best = scs[0];
    int arg = 0;
    for (int nn = 1; nn < NN_; nn++)
      if (scs[nn] > best) { best = scs[nn]; arg = nn; }  // first-max like jnp.argmax
    node[p] = arg;
  }
  float mag = block_sum256(hv * mag_w[t], red) + mag_b[0];
  float sig = 1.0f / (1.0f + __expf(-mag));
  h[(size_t)p * D_ + t] = hv + delta[(size_t)p * D_ + t] * sig;
}

// ---------------- final logits ----------------
__global__ __launch_bounds__(256) void out_kernel(const float* __restrict__ h,
                                                  const float* __restrict__ ow,
                                                  const float* __restrict__ ob,
                                                  float* __restrict__ out) {
  int p = blockIdx.x, t = threadIdx.x;
  __shared__ float hs[D_];
  __shared__ float part[8][NC_];
  hs[t] = h[(size_t)p * D_ + t];
  __syncthreads();
  int j = t & 31, seg = t >> 5;
  float s = 0.0f;
#pragma unroll 8
  for (int i = 0; i < 32; i++) {
    int ii = seg * 32 + i;
    s += hs[ii] * ow[ii * NC_ + j];
  }
  part[seg][j] = s;
  __syncthreads();
  if (t < NC_) {
    float r = ob[t];
#pragma unroll
    for (int g = 0; g < 8; g++) r += part[g][t];
    out[(size_t)p * NC_ + t] = r;
  }
}

extern "C" void kernel_launch(void* const* d_in, const int* in_sizes, int n_in,
                              void* d_out, int out_size, void* d_ws, size_t ws_size,
                              hipStream_t stream) {
  (void)in_sizes; (void)n_in; (void)out_size; (void)ws_size;
  const float* query_keys       = (const float*)d_in[0];
  const float* writer_keys      = (const float*)d_in[1];
  const float* key_proj_w       = (const float*)d_in[2];
  const float* key_proj_b       = (const float*)d_in[3];
  const float* class_embed      = (const float*)d_in[4];
  const float* role_embed       = (const float*)d_in[5];
  const float* start_node_embed = (const float*)d_in[6];
  const float* input_ln_g       = (const float*)d_in[7];
  const float* input_ln_b       = (const float*)d_in[8];
  const float* ln1_g            = (const float*)d_in[9];
  const float* ln1_b            = (const float*)d_in[10];
  const float* wqkv             = (const float*)d_in[11];
  const float* bqkv             = (const float*)d_in[12];
  const float* wo               = (const float*)d_in[13];
  const float* bo               = (const float*)d_in[14];
  const float* ln2_g            = (const float*)d_in[15];
  const float* ln2_b            = (const float*)d_in[16];
  const float* w_fc1            = (const float*)d_in[17];
  const float* b_fc1            = (const float*)d_in[18];
  const float* w_fc2            = (const float*)d_in[19];
  const float* b_fc2            = (const float*)d_in[20];
  const float* delta_w          = (const float*)d_in[21];
  const float* delta_b          = (const float*)d_in[22];
  const float* dir_w            = (const float*)d_in[23];
  const float* dir_b            = (const float*)d_in[24];
  const float* mag_w            = (const float*)d_in[25];
  const float* mag_b            = (const float*)d_in[26];
  const float* out_w            = (const float*)d_in[27];
  const float* out_b            = (const float*)d_in[28];
  const float* address_table    = (const float*)d_in[29];
  const int* query_start_nodes  = (const int*)d_in[30];
  const int* writer_labels      = (const int*)d_in[31];
  const int* writer_start_nodes = (const int*)d_in[32];

  uintptr_t basep = (uintptr_t)d_ws;
  auto carve = [&](size_t bytes) {
    basep = (basep + 255) & ~(uintptr_t)255;
    void* r = (void*)basep;
    basep += bytes;
    return r;
  };
  // Buffer roles (all padded +16 rows: 16-row tail tiles may prefetch past P):
  //  h    : packet-space residual stream
  //  x    : sorted space: ln output / attn output (ao)
  //  buf1 : sorted qkv main [P x 768]; reused as delta out [P x 256]
  //  ff   : sorted fc1 output [P x 1024]
  //  pbuf : fc2 z1 partial [P x 256] (folded by delta-glin XMODE=1 and route)
  float* h    = (float*)carve((size_t)(P_ + 16) * D_ * 4);
  float* x    = (float*)carve((size_t)(P_ + 16) * D_ * 4);
  float* buf1 = (float*)carve((size_t)(P_ + 16) * DFF_ * 4);
  float* ff   = (float*)carve((size_t)(P_ + 16) * DFF_ * 4);
  float* pbuf = (float*)carve((size_t)(P_ + 16) * D_ * 4);
  int* node   = (int*)carve(P_ * 4);
  int* order  = (int*)carve(P_ * 4);
  int* invord = (int*)carve(P_ * 4);
  int* offs   = (int*)carve(NN_ * 4);
  int* cnts   = (int*)carve(NN_ * 4);
  int* tnode  = (int*)carve(MAXT2_ * 4);
  int* tstart = (int*)carve(MAXT2_ * 4);
  int* tend   = (int*)carve(MAXT2_ * 4);
  int* ntiles = (int*)carve(4);

  encode_kernel<<<P_, 256, 0, stream>>>(query_keys, writer_keys, key_proj_w, key_proj_b,
                                        class_embed, role_embed, start_node_embed,
                                        input_ln_g, input_ln_b, query_start_nodes,
                                        writer_labels, writer_start_nodes, h, node);

  for (int hop = 0; hop < HOPS_; ++hop) {
    sort_kernel<<<1, 256, 0, stream>>>(node, order, invord, offs, cnts,
                                       tnode, tstart, tend, ntiles);
    ln_affine<<<P_ / 4, 256, 0, stream>>>(h, ln1_g, ln1_b, node, order, x);
    // qkv: [256 -> 768], sorted out
    glin2<256, 768, 0, 0, 1, 1, 0><<<dim3(MAXT2_, 3), 256, 0, stream>>>(
        x, wqkv, bqkv, buf1, nullptr, nullptr, order, invord, tnode, tstart, tend,
        ntiles);
    attn_kernel<<<dim3(P_ / 32, NH_), 256, 0, stream>>>(buf1, node, order, offs,
                                                        cnts, x /*ao, sorted*/);
    // wo: [256 -> 256], residual into h (packet space)
    glin2<256, 256, 0, 1, 1, 1, 0><<<dim3(MAXT2_, 1), 256, 0, stream>>>(
        x, wo, bo, h, nullptr, nullptr, order, invord, tnode, tstart, tend, ntiles);
    ln_affine<<<P_ / 4, 256, 0, stream>>>(h, ln2_g, ln2_b, node, order, x);
    // fc1: [256 -> 1024], GELU, sorted out
    glin2<256, 1024, 1, 0, 1, 1, 0><<<dim3(MAXT2_, 4), 256, 0, stream>>>(
        x, w_fc1, b_fc1, ff, nullptr, nullptr, order, invord, tnode, tstart, tend,
        ntiles);
    // fc2: [1024 -> 256], KSPLIT=2: z0 resid into h, z1 raw partial -> pbuf
    glin2<1024, 256, 0, 1, 1, 2, 0><<<dim3(MAXT2_, 1, 2), 256, 0, stream>>>(
        ff, w_fc2, b_fc2, h, pbuf, nullptr, order, invord, tnode, tstart, tend,
        ntiles);
    // delta = (h + pbuf) @ delta_w + delta_b   (dense, packet space, XMODE=1)
    glin2<256, 256, 0, 0, 0, 1, 1><<<dim3(P_ / 16, 1), 256, 0, stream>>>(
        h, delta_w, delta_b, buf1 /*delta out*/, nullptr, pbuf, order, invord,
        tnode, tstart, tend, ntiles);
    route_kernel<<<P_, 256, 0, stream>>>(h, pbuf, invord, dir_w, dir_b, address_table,
                                         mag_w, mag_b, buf1, node);
  }

  out_kernel<<<P_, 256, 0, stream>>>(h, out_w, out_b, (float*)d_out);
}